// Round 5
// baseline (468.269 us; speedup 1.0000x reference)
//
#include <hip/hip_runtime.h>

// ScaledDotProductAttention fwd: out0 = attn output [2,16,2048,64] f32,
// out1 = attn weights [2,16,2048,2048] f32.
// Round 5: pass2 store-coalescing fix. Pass2 = standalone weight-stream kernel
// with UNSWAPPED mfma (D: col=k=l15 -> 16 lanes store 64B-contiguous sectors;
// round-4's swapped layout scattered 16B/lane 8KB apart = 4x write
// amplification). kt split x8 (8192 blocks), K prefetch, no LDS, no barriers.
// Pass1 = round-4 minus K-prefetch (VGPR <=128 so 4 blocks/CU stay resident).

typedef __attribute__((ext_vector_type(4))) float f32x4;
typedef __attribute__((ext_vector_type(8))) short s16x8;
typedef __attribute__((ext_vector_type(4))) unsigned short u16x4;

#define S_LEN 2048
#define D_DIM 64
#define H_NUM 16
#define B_NUM 2
#define NT    32   // S/64 k-tiles
#define SW    32   // mask words per row (S/64)

__device__ __forceinline__ int swz(int row, int colByte) {
  return row * 128 + (colByte ^ ((row & 7) << 4));
}

__device__ __forceinline__ unsigned short f2bf(float f) {  // RNE f32->bf16
  unsigned int x = __builtin_bit_cast(unsigned int, f);
  x = (x + 0x7FFFu + ((x >> 16) & 1u)) >> 16;
  return (unsigned short)x;
}

__device__ __forceinline__ f32x4 mfma16(f32x4 acc, s16x8 a, s16x8 b) {
  return __builtin_amdgcn_mfma_f32_16x16x32_bf16(a, b, acc, 0, 0, 0);
}

// ---------------- prep kernels ----------------

__global__ __launch_bounds__(256) void mask_pack_kernel(const int* __restrict__ m,
                                                        unsigned long long* __restrict__ bits) {
  const int total = B_NUM * S_LEN * S_LEN;
  const int step  = gridDim.x * blockDim.x;
  for (int i = blockIdx.x * blockDim.x + threadIdx.x; i < total; i += step) {
    unsigned long long b = __ballot(m[i] != 0);
    if ((threadIdx.x & 63) == 0) bits[i >> 6] = b;
  }
}

__global__ __launch_bounds__(256) void cvt_qk_kernel(const float* __restrict__ Q,
                                                     const float* __restrict__ K,
                                                     u16x4* __restrict__ Q16,
                                                     u16x4* __restrict__ K16) {
  const int n4 = B_NUM * H_NUM * S_LEN * D_DIM / 4;
  const int step = gridDim.x * blockDim.x;
  for (int i = blockIdx.x * blockDim.x + threadIdx.x; i < n4; i += step) {
    float4 q = ((const float4*)Q)[i];
    Q16[i] = u16x4{f2bf(q.x), f2bf(q.y), f2bf(q.z), f2bf(q.w)};
    float4 k = ((const float4*)K)[i];
    K16[i] = u16x4{f2bf(k.x), f2bf(k.y), f2bf(k.z), f2bf(k.w)};
  }
}

__global__ __launch_bounds__(256) void v_transpose_kernel(const float* __restrict__ V,
                                                          unsigned short* __restrict__ VT) {
  __shared__ unsigned short t[64][72];
  const int bh = blockIdx.x >> 5;
  const int st = blockIdx.x & 31;
  const float* src = V + ((size_t)bh * S_LEN + st * 64) * D_DIM;
  const int r0 = threadIdx.x >> 4;
  const int c  = (threadIdx.x & 15) * 4;
#pragma unroll
  for (int i = 0; i < 4; ++i) {
    const int r = r0 + i * 16;
    float4 v = *(const float4*)(src + r * D_DIM + c);
    t[c + 0][r] = f2bf(v.x); t[c + 1][r] = f2bf(v.y);
    t[c + 2][r] = f2bf(v.z); t[c + 3][r] = f2bf(v.w);
  }
  __syncthreads();
#pragma unroll
  for (int i = 0; i < 4; ++i) {
    const int idx = threadIdx.x + i * 256;
    const int d = idx >> 4;
    const int s4 = (idx & 15) * 4;
    u16x4 o = {t[d][s4], t[d][s4 + 1], t[d][s4 + 2], t[d][s4 + 3]};
    *(u16x4*)(VT + ((size_t)bh * D_DIM + d) * S_LEN + st * 64 + s4) = o;
  }
}

// ---------------- pass 1: O + reciprocal rowsum ----------------

__global__ __launch_bounds__(256) void attn_pass1_kernel(
    const unsigned short* __restrict__ Q16, const unsigned short* __restrict__ K16,
    const unsigned short* __restrict__ VT16, const unsigned long long* __restrict__ Mb,
    float* __restrict__ Op, float* __restrict__ lpq)
{
  const int tid  = threadIdx.x;
  const int lane = tid & 63;
  const int wv   = tid >> 6;
  const int l15  = lane & 15;
  const int g4   = lane >> 4;

  const int wg = blockIdx.x;                 // 1024 blocks
  const int lg = (wg & 7) * 128 + (wg >> 3); // bijective XCD swizzle
  const int qt = lg & 31;
  const int bh = lg >> 5;
  const int b  = bh >> 4;

  __shared__ __align__(16) char PsAll[4 * 2 * 2048];
  char* Ps0 = PsAll + (wv << 12);

  const unsigned short* Qg = Q16 + ((size_t)bh * S_LEN + qt * 64 + wv * 16 + l15) * D_DIM + g4 * 8;
  const unsigned short* Kg = K16 + (size_t)bh * S_LEN * D_DIM;
  const unsigned short* Vg = VT16 + (size_t)bh * D_DIM * S_LEN;
  float* Og = Op + ((size_t)bh * S_LEN + qt * 64) * D_DIM;
  float* lpg = lpq + (size_t)bh * S_LEN + qt * 64;
  const unsigned long long* Mg = Mb + ((size_t)b * S_LEN + qt * 64) * SW;

  const s16x8 qa0 = *(const s16x8*)Qg;
  const s16x8 qa1 = *(const s16x8*)(Qg + 32);

  f32x4 oacc[4];
#pragma unroll
  for (int i = 0; i < 4; ++i) oacc[i] = f32x4{0.f, 0.f, 0.f, 0.f};
  float lp[4] = {0.f, 0.f, 0.f, 0.f};

  const int qrow = wv * 16 + g4 * 4;

  for (int kt = 0; kt < NT; ++kt) {
    char* Ps = Ps0 + ((kt & 1) << 11);

    f32x4 sacc[4];
#pragma unroll
    for (int i = 0; i < 4; ++i) sacc[i] = f32x4{0.f, 0.f, 0.f, 0.f};
#pragma unroll
    for (int ct = 0; ct < 4; ++ct) {
      const unsigned short* kp = Kg + (size_t)(kt * 64 + ct * 16 + l15) * D_DIM + g4 * 8;
      s16x8 b0 = *(const s16x8*)kp;
      s16x8 b1 = *(const s16x8*)(kp + 32);
      sacc[ct] = mfma16(sacc[ct], qa0, b0);
      sacc[ct] = mfma16(sacc[ct], qa1, b1);
    }

    // hoist V loads: in flight during exp/LDS section and lgkm drain
    s16x8 vv0[4], vv1[4];
#pragma unroll
    for (int ct = 0; ct < 4; ++ct) {
      const unsigned short* vp = Vg + (size_t)(ct * 16 + l15) * S_LEN + kt * 64 + g4 * 8;
      vv0[ct] = *(const s16x8*)vp;
      vv1[ct] = *(const s16x8*)(vp + 32);
    }

    unsigned long long mw[4];
#pragma unroll
    for (int r = 0; r < 4; ++r) mw[r] = Mg[(qrow + r) * SW + kt];

#pragma unroll
    for (int ct = 0; ct < 4; ++ct) {
#pragma unroll
      for (int r = 0; r < 4; ++r) {
        float e = __expf(sacc[ct][r] * 0.125f);
        e = ((mw[r] >> (ct * 16 + l15)) & 1ull) ? e : 0.f;
        lp[r] += e;
        *(unsigned short*)(Ps + swz(g4 * 4 + r, (ct * 16 + l15) * 2)) = f2bf(e);
      }
    }
    // wave-internal cross-lane LDS hazard: drain DS queue, pin reads after
    asm volatile("s_waitcnt lgkmcnt(0)" ::: "memory");
    __builtin_amdgcn_sched_barrier(0);

    const s16x8 pa0 = *(const s16x8*)(Ps + swz(l15, g4 * 16));
    const s16x8 pa1 = *(const s16x8*)(Ps + swz(l15, g4 * 16 + 64));
#pragma unroll
    for (int ct = 0; ct < 4; ++ct) {
      oacc[ct] = mfma16(oacc[ct], pa0, vv0[ct]);
      oacc[ct] = mfma16(oacc[ct], pa1, vv1[ct]);
    }
  }

  // rowsum reduce across the 16-lane column group; keep reciprocal
#pragma unroll
  for (int r = 0; r < 4; ++r) {
    float v = lp[r];
    v += __shfl_xor(v, 1);
    v += __shfl_xor(v, 2);
    v += __shfl_xor(v, 4);
    v += __shfl_xor(v, 8);
    lp[r] = 1.0f / v;
  }

#pragma unroll
  for (int ct = 0; ct < 4; ++ct)
#pragma unroll
    for (int r = 0; r < 4; ++r)
      Og[(size_t)(qrow + r) * D_DIM + ct * 16 + l15] = oacc[ct][r] * lp[r];

  // store reciprocal rowsum for pass 2 (lp[r] uniform across l15 group)
#pragma unroll
  for (int r = 0; r < 4; ++r)
    if (l15 == r) lpg[qrow + r] = lp[r];
}

// ---------------- pass 2: stream weights (unswapped, coalesced stores) ----------------

__global__ __launch_bounds__(256) void attn_pass2_kernel(
    const unsigned short* __restrict__ Q16, const unsigned short* __restrict__ K16,
    const unsigned long long* __restrict__ Mb, const float* __restrict__ lpq,
    float* __restrict__ Wp)
{
  const int tid  = threadIdx.x;
  const int lane = tid & 63;
  const int wv   = tid >> 6;
  const int l15  = lane & 15;
  const int g4   = lane >> 4;

  const int wg = blockIdx.x;                  // 8192 blocks
  const int lg = (wg & 7) * 1024 + (wg >> 3); // bijective XCD swizzle
  const int qt   = lg & 31;                   // q tile
  const int rest = lg >> 5;
  const int kc   = rest & 7;                  // kt chunk (4 kt each)
  const int bh   = rest >> 3;
  const int b    = bh >> 4;

  const int qrow = wv * 16 + g4 * 4;          // first of this lane's 4 rows (in-tile)

  const unsigned short* Qg = Q16 + ((size_t)bh * S_LEN + qt * 64 + wv * 16 + l15) * D_DIM + g4 * 8;
  const unsigned short* Kg = K16 + (size_t)bh * S_LEN * D_DIM;
  float* Wg = Wp + ((size_t)bh * S_LEN + qt * 64) * S_LEN;
  const unsigned long long* Mg = Mb + ((size_t)b * S_LEN + qt * 64) * SW;

  const s16x8 qa0 = *(const s16x8*)Qg;
  const s16x8 qa1 = *(const s16x8*)(Qg + 32);

  float lpr[4];
#pragma unroll
  for (int r = 0; r < 4; ++r) lpr[r] = lpq[(size_t)bh * S_LEN + qt * 64 + qrow + r];

  const int kt0 = kc * 4;

  // prefetch K frags for first kt
  s16x8 kb0[4], kb1[4];
#pragma unroll
  for (int ct = 0; ct < 4; ++ct) {
    const unsigned short* kp = Kg + (size_t)(kt0 * 64 + ct * 16 + l15) * D_DIM + g4 * 8;
    kb0[ct] = *(const s16x8*)kp;
    kb1[ct] = *(const s16x8*)(kp + 32);
  }

  for (int kt = kt0; kt < kt0 + 4; ++kt) {
    // prefetch next kt (clamped)
    const int ktn = (kt < kt0 + 3) ? kt + 1 : kt;
    s16x8 nk0[4], nk1[4];
#pragma unroll
    for (int ct = 0; ct < 4; ++ct) {
      const unsigned short* kp = Kg + (size_t)(ktn * 64 + ct * 16 + l15) * D_DIM + g4 * 8;
      nk0[ct] = *(const s16x8*)kp;
      nk1[ct] = *(const s16x8*)(kp + 32);
    }

    unsigned long long mw[4];
#pragma unroll
    for (int r = 0; r < 4; ++r) mw[r] = Mg[(qrow + r) * SW + kt];

    f32x4 sacc[4];
#pragma unroll
    for (int i = 0; i < 4; ++i) sacc[i] = f32x4{0.f, 0.f, 0.f, 0.f};
#pragma unroll
    for (int ct = 0; ct < 4; ++ct) {
      sacc[ct] = mfma16(sacc[ct], qa0, kb0[ct]);
      sacc[ct] = mfma16(sacc[ct], qa1, kb1[ct]);
    }

    // D layout: row = qrow + r, col = ct*16 + l15  -> 16 lanes (l15) store
    // 16 consecutive floats = 64B sector-aligned chunks, 4 rows per instr.
#pragma unroll
    for (int ct = 0; ct < 4; ++ct) {
#pragma unroll
      for (int r = 0; r < 4; ++r) {
        float e = __expf(sacc[ct][r] * 0.125f);
        e = ((mw[r] >> (ct * 16 + l15)) & 1ull) ? e * lpr[r] : 0.f;
        __builtin_nontemporal_store(e,
            Wg + (size_t)(qrow + r) * S_LEN + kt * 64 + ct * 16 + l15);
      }
    }
#pragma unroll
    for (int ct = 0; ct < 4; ++ct) { kb0[ct] = nk0[ct]; kb1[ct] = nk1[ct]; }
  }
}

// ---------------- fallback (fp32 inputs, LDS-staged) ----------------

template <int USE_BITS>
__global__ __launch_bounds__(256) void attn_fwd_kernel(
    const float* __restrict__ Qp, const float* __restrict__ Kp, const float* __restrict__ Vp,
    const unsigned long long* __restrict__ Mb, const int* __restrict__ Mi,
    float* __restrict__ Op, float* __restrict__ Wp)
{
  const int tid  = threadIdx.x;
  const int lane = tid & 63;
  const int wv   = tid >> 6;
  const int l15  = lane & 15;
  const int g4   = lane >> 4;

  const int wg = blockIdx.x;
  const int lg = (wg & 7) * 128 + (wg >> 3);
  const int qt = lg & 31;
  const int bh = lg >> 5;
  const int b  = bh >> 4;

  __shared__ __align__(16) char lds[32768];
  char* Qs  = lds;
  char* Ks  = lds + 8192;
  char* VTs = lds + 16384;
  char* Ps  = lds + 24576 + (wv << 11);

  const float* Qg = Qp + ((size_t)bh * S_LEN + qt * 64) * D_DIM;
  const float* Kg = Kp + (size_t)bh * S_LEN * D_DIM;
  const float* Vg = Vp + (size_t)bh * S_LEN * D_DIM;
  float* Og = Op + ((size_t)bh * S_LEN + qt * 64) * D_DIM;
  float* Wg = Wp + ((size_t)bh * S_LEN + qt * 64) * S_LEN;
  const unsigned long long* Mg = Mb + ((size_t)b * S_LEN + qt * 64) * SW;
  const int* Mig = Mi + ((size_t)b * S_LEN + qt * 64) * S_LEN;

  {
    const int r0 = tid >> 4;
    const int c  = (tid & 15) * 4;
#pragma unroll
    for (int i = 0; i < 4; ++i) {
      const int r = r0 + i * 16;
      float4 v = *(const float4*)(Qg + r * D_DIM + c);
      ushort4 p; p.x = f2bf(v.x); p.y = f2bf(v.y); p.z = f2bf(v.z); p.w = f2bf(v.w);
      *(ushort4*)(Qs + swz(r, c * 2)) = p;
    }
  }
  __syncthreads();
  const s16x8 qa0 = *(const s16x8*)(Qs + swz(wv * 16 + l15, g4 * 16));
  const s16x8 qa1 = *(const s16x8*)(Qs + swz(wv * 16 + l15, g4 * 16 + 64));

  f32x4 oacc[4];
#pragma unroll
  for (int i = 0; i < 4; ++i) oacc[i] = f32x4{0.f, 0.f, 0.f, 0.f};
  float lp[4] = {0.f, 0.f, 0.f, 0.f};

  const int qrow = wv * 16 + g4 * 4;

  for (int kt = 0; kt < NT; ++kt) {
    __syncthreads();
    {
      const int r0 = tid >> 4;
      const int c  = (tid & 15) * 4;
      const float* Kt = Kg + kt * 64 * D_DIM;
#pragma unroll
      for (int i = 0; i < 4; ++i) {
        const int r = r0 + i * 16;
        float4 v = *(const float4*)(Kt + r * D_DIM + c);
        ushort4 p; p.x = f2bf(v.x); p.y = f2bf(v.y); p.z = f2bf(v.z); p.w = f2bf(v.w);
        *(ushort4*)(Ks + swz(r, c * 2)) = p;
      }
      const float* Vt = Vg + kt * 64 * D_DIM;
#pragma unroll
      for (int i = 0; i < 2; ++i) {
        const int rr = (tid >> 4) * 2 + i * 32;
        float4 a  = *(const float4*)(Vt + rr * D_DIM + c);
        float4 bq = *(const float4*)(Vt + (rr + 1) * D_DIM + c);
        const float av[4] = {a.x, a.y, a.z, a.w};
        const float bv[4] = {bq.x, bq.y, bq.z, bq.w};
#pragma unroll
        for (int j = 0; j < 4; ++j) {
          unsigned pk = (unsigned)f2bf(av[j]) | ((unsigned)f2bf(bv[j]) << 16);
          *(unsigned*)(VTs + swz(c + j, rr * 2)) = pk;
        }
      }
    }
    __syncthreads();

    unsigned long long mw[4] = {0, 0, 0, 0};
    if (USE_BITS) {
#pragma unroll
      for (int r = 0; r < 4; ++r) mw[r] = Mg[(qrow + r) * SW + kt];
    }

    f32x4 sacc[4];
#pragma unroll
    for (int i = 0; i < 4; ++i) sacc[i] = f32x4{0.f, 0.f, 0.f, 0.f};
#pragma unroll
    for (int ct = 0; ct < 4; ++ct) {
      s16x8 b0 = *(const s16x8*)(Ks + swz(ct * 16 + l15, g4 * 16));
      s16x8 b1 = *(const s16x8*)(Ks + swz(ct * 16 + l15, g4 * 16 + 64));
      sacc[ct] = mfma16(sacc[ct], qa0, b0);
      sacc[ct] = mfma16(sacc[ct], qa1, b1);
    }

#pragma unroll
    for (int ct = 0; ct < 4; ++ct) {
#pragma unroll
      for (int r = 0; r < 4; ++r) {
        float e = __expf(sacc[ct][r] * 0.125f);
        bool keep;
        if (USE_BITS) keep = (mw[r] >> (ct * 16 + l15)) & 1ull;
        else          keep = Mig[(size_t)(qrow + r) * S_LEN + kt * 64 + ct * 16 + l15] != 0;
        e = keep ? e : 0.f;
        lp[r] += e;
        *(unsigned short*)(Ps + swz(g4 * 4 + r, (ct * 16 + l15) * 2)) = f2bf(e);
      }
    }
    asm volatile("s_waitcnt lgkmcnt(0)" ::: "memory");
    __builtin_amdgcn_sched_barrier(0);

    const s16x8 pa0 = *(const s16x8*)(Ps + swz(l15, g4 * 16));
    const s16x8 pa1 = *(const s16x8*)(Ps + swz(l15, g4 * 16 + 64));
#pragma unroll
    for (int ct = 0; ct < 4; ++ct) {
      s16x8 v0 = *(const s16x8*)(VTs + swz(ct * 16 + l15, g4 * 16));
      s16x8 v1 = *(const s16x8*)(VTs + swz(ct * 16 + l15, g4 * 16 + 64));
      oacc[ct] = mfma16(oacc[ct], pa0, v0);
      oacc[ct] = mfma16(oacc[ct], pa1, v1);
    }
  }

#pragma unroll
  for (int r = 0; r < 4; ++r) {
    float v = lp[r];
    v += __shfl_xor(v, 1);
    v += __shfl_xor(v, 2);
    v += __shfl_xor(v, 4);
    v += __shfl_xor(v, 8);
    lp[r] = 1.0f / v;
  }

#pragma unroll
  for (int ct = 0; ct < 4; ++ct)
#pragma unroll
    for (int r = 0; r < 4; ++r)
      Og[(size_t)(qrow + r) * D_DIM + ct * 16 + l15] = oacc[ct][r] * lp[r];

  for (int kt = 0; kt < NT; ++kt) {
    __syncthreads();
    {
      const int r0 = tid >> 4;
      const int c  = (tid & 15) * 4;
      const float* Kt = Kg + kt * 64 * D_DIM;
#pragma unroll
      for (int i = 0; i < 4; ++i) {
        const int r = r0 + i * 16;
        float4 v = *(const float4*)(Kt + r * D_DIM + c);
        ushort4 p; p.x = f2bf(v.x); p.y = f2bf(v.y); p.z = f2bf(v.z); p.w = f2bf(v.w);
        *(ushort4*)(Ks + swz(r, c * 2)) = p;
      }
    }
    __syncthreads();

    unsigned long long mw[4] = {0, 0, 0, 0};
    if (USE_BITS) {
#pragma unroll
      for (int r = 0; r < 4; ++r) mw[r] = Mg[(qrow + r) * SW + kt];
    }

    f32x4 sacc[4];
#pragma unroll
    for (int i = 0; i < 4; ++i) sacc[i] = f32x4{0.f, 0.f, 0.f, 0.f};
#pragma unroll
    for (int ct = 0; ct < 4; ++ct) {
      s16x8 b0 = *(const s16x8*)(Ks + swz(ct * 16 + l15, g4 * 16));
      s16x8 b1 = *(const s16x8*)(Ks + swz(ct * 16 + l15, g4 * 16 + 64));
      sacc[ct] = mfma16(sacc[ct], qa0, b0);
      sacc[ct] = mfma16(sacc[ct], qa1, b1);
    }

#pragma unroll
    for (int ct = 0; ct < 4; ++ct) {
#pragma unroll
      for (int r = 0; r < 4; ++r) {
        float e = __expf(sacc[ct][r] * 0.125f);
        bool keep;
        if (USE_BITS) keep = (mw[r] >> (ct * 16 + l15)) & 1ull;
        else          keep = Mig[(size_t)(qrow + r) * S_LEN + kt * 64 + ct * 16 + l15] != 0;
        e = keep ? e : 0.f;
        __builtin_nontemporal_store(e * lp[r],
            Wg + (size_t)(qrow + r) * S_LEN + kt * 64 + ct * 16 + l15);
      }
    }
  }
}

extern "C" void kernel_launch(void* const* d_in, const int* in_sizes, int n_in,
                              void* d_out, int out_size, void* d_ws, size_t ws_size,
                              hipStream_t stream) {
  (void)in_sizes; (void)n_in; (void)out_size;
  const float* Q   = (const float*)d_in[0];
  const float* K   = (const float*)d_in[1];
  const float* V   = (const float*)d_in[2];
  const int* mask  = (const int*)d_in[3];
  float* Out = (float*)d_out;
  float* W   = Out + (size_t)B_NUM * H_NUM * S_LEN * D_DIM;

  const size_t bits_bytes = (size_t)(B_NUM * S_LEN * S_LEN / 64) * 8;      // 1 MiB
  const size_t t16_bytes  = (size_t)B_NUM * H_NUM * S_LEN * D_DIM * 2;     // 8 MiB
  const size_t lp_bytes   = (size_t)B_NUM * H_NUM * S_LEN * 4;             // 256 KiB
  unsigned long long* bits = (unsigned long long*)d_ws;

  if (ws_size >= bits_bytes + 3 * t16_bytes + lp_bytes) {
    unsigned short* Q16 = (unsigned short*)((char*)d_ws + bits_bytes);
    unsigned short* K16 = Q16 + t16_bytes / 2;
    unsigned short* VT  = K16 + t16_bytes / 2;
    float* lpq = (float*)((char*)d_ws + bits_bytes + 3 * t16_bytes);
    mask_pack_kernel<<<1024, 256, 0, stream>>>(mask, bits);
    cvt_qk_kernel<<<2048, 256, 0, stream>>>(Q, K, (u16x4*)Q16, (u16x4*)K16);
    v_transpose_kernel<<<1024, 256, 0, stream>>>(V, VT);
    attn_pass1_kernel<<<1024, 256, 0, stream>>>(Q16, K16, VT, bits, Out, lpq);
    attn_pass2_kernel<<<8192, 256, 0, stream>>>(Q16, K16, bits, lpq, W);
  } else if (ws_size >= bits_bytes) {
    mask_pack_kernel<<<1024, 256, 0, stream>>>(mask, bits);
    attn_fwd_kernel<1><<<1024, 256, 0, stream>>>(Q, K, V, bits, mask, Out, W);
  } else {
    attn_fwd_kernel<0><<<1024, 256, 0, stream>>>(Q, K, V, bits, mask, Out, W);
  }
}

// Round 6
// 266.384 us; speedup vs baseline: 1.7579x; 1.7579x over previous
//
#include <hip/hip_runtime.h>

// ScaledDotProductAttention fwd: out0 = attn output [2,16,2048,64] f32,
// out1 = attn weights [2,16,2048,2048] f32.
// Round 6: round-1 monolith (best, 259us) + two fixes:
//  (1) V staged from pre-transposed VT16 (prep kernel) with the same
//      conflict-free pattern as K staging — kills the 1.47e7 8-way bank
//      conflicts of the in-kernel V transpose writes.
//  (2) pass-2 reads K frags directly from global bf16 (L2-hot, register
//      prefetch) — removes 64 barrier+vmcnt(0) drains from the 537MB
//      weight store stream. Pass 2 stays fused (Q frags + lp in regs).

typedef __attribute__((ext_vector_type(4))) float f32x4;
typedef __attribute__((ext_vector_type(8))) short s16x8;
typedef __attribute__((ext_vector_type(4))) unsigned short u16x4;

#define S_LEN 2048
#define D_DIM 64
#define H_NUM 16
#define B_NUM 2
#define NT    32   // S/64 k-tiles
#define SW    32   // mask words per row (S/64)

__device__ __forceinline__ int swz(int row, int colByte) {
  return row * 128 + (colByte ^ ((row & 7) << 4));
}

__device__ __forceinline__ unsigned short f2bf(float f) {  // RNE f32->bf16
  unsigned int x = __builtin_bit_cast(unsigned int, f);
  x = (x + 0x7FFFu + ((x >> 16) & 1u)) >> 16;
  return (unsigned short)x;
}

__device__ __forceinline__ f32x4 mfma16(f32x4 acc, s16x8 a, s16x8 b) {
  return __builtin_amdgcn_mfma_f32_16x16x32_bf16(a, b, acc, 0, 0, 0);
}

// ---------------- prep kernels ----------------

__global__ __launch_bounds__(256) void mask_pack_kernel(const int* __restrict__ m,
                                                        unsigned long long* __restrict__ bits) {
  const int total = B_NUM * S_LEN * S_LEN;
  const int step  = gridDim.x * blockDim.x;
  for (int i = blockIdx.x * blockDim.x + threadIdx.x; i < total; i += step) {
    unsigned long long b = __ballot(m[i] != 0);
    if ((threadIdx.x & 63) == 0) bits[i >> 6] = b;
  }
}

__global__ __launch_bounds__(256) void cvt_k_kernel(const float* __restrict__ K,
                                                    u16x4* __restrict__ K16) {
  const int n4 = B_NUM * H_NUM * S_LEN * D_DIM / 4;  // 524288
  const int step = gridDim.x * blockDim.x;
  for (int i = blockIdx.x * blockDim.x + threadIdx.x; i < n4; i += step) {
    float4 k = ((const float4*)K)[i];
    K16[i] = u16x4{f2bf(k.x), f2bf(k.y), f2bf(k.z), f2bf(k.w)};
  }
}

__global__ __launch_bounds__(256) void v_transpose_kernel(const float* __restrict__ V,
                                                          unsigned short* __restrict__ VT) {
  __shared__ unsigned short t[64][72];
  const int bh = blockIdx.x >> 5;   // grid 1024
  const int st = blockIdx.x & 31;
  const float* src = V + ((size_t)bh * S_LEN + st * 64) * D_DIM;
  const int r0 = threadIdx.x >> 4;
  const int c  = (threadIdx.x & 15) * 4;
#pragma unroll
  for (int i = 0; i < 4; ++i) {
    const int r = r0 + i * 16;
    float4 v = *(const float4*)(src + r * D_DIM + c);
    t[c + 0][r] = f2bf(v.x); t[c + 1][r] = f2bf(v.y);
    t[c + 2][r] = f2bf(v.z); t[c + 3][r] = f2bf(v.w);
  }
  __syncthreads();
#pragma unroll
  for (int i = 0; i < 4; ++i) {
    const int idx = threadIdx.x + i * 256;
    const int d = idx >> 4;
    const int s4 = (idx & 15) * 4;
    u16x4 o = {t[d][s4], t[d][s4 + 1], t[d][s4 + 2], t[d][s4 + 3]};
    *(u16x4*)(VT + ((size_t)bh * D_DIM + d) * S_LEN + st * 64 + s4) = o;
  }
}

// ---------------- fused main kernel ----------------

__global__ __launch_bounds__(256) void attn_fused_kernel(
    const float* __restrict__ Qp, const float* __restrict__ Kp,
    const unsigned short* __restrict__ K16, const unsigned short* __restrict__ VT16,
    const unsigned long long* __restrict__ Mb,
    float* __restrict__ Op, float* __restrict__ Wp)
{
  const int tid  = threadIdx.x;
  const int lane = tid & 63;
  const int wv   = tid >> 6;
  const int l15  = lane & 15;
  const int g4   = lane >> 4;

  const int wg = blockIdx.x;                 // 1024 blocks
  const int lg = (wg & 7) * 128 + (wg >> 3); // bijective XCD swizzle
  const int qt = lg & 31;
  const int bh = lg >> 5;
  const int b  = bh >> 4;

  __shared__ __align__(16) char lds[32768];
  char* Qs  = lds;                           // [64 q][64 d] bf16 swz
  char* Ks  = lds + 8192;                    // [64 k][64 d] bf16 swz
  char* VTs = lds + 16384;                   // [64 d][64 s] bf16 swz
  char* Ps  = lds + 24576 + (wv << 11);      // per-wave [16][64] bf16 swz

  const float* Qg = Qp + ((size_t)bh * S_LEN + qt * 64) * D_DIM;
  const float* Kg = Kp + (size_t)bh * S_LEN * D_DIM;
  const unsigned short* Kg16 = K16 + (size_t)bh * S_LEN * D_DIM;
  const unsigned short* Vg   = VT16 + (size_t)bh * D_DIM * S_LEN;
  float* Og = Op + ((size_t)bh * S_LEN + qt * 64) * D_DIM;
  float* Wg = Wp + ((size_t)bh * S_LEN + qt * 64) * S_LEN;
  const unsigned long long* Mg = Mb + ((size_t)b * S_LEN + qt * 64) * SW;

  // ---- stage Q once ----
  {
    const int r0 = tid >> 4;
    const int c  = (tid & 15) * 4;
#pragma unroll
    for (int i = 0; i < 4; ++i) {
      const int r = r0 + i * 16;
      float4 v = *(const float4*)(Qg + r * D_DIM + c);
      ushort4 p; p.x = f2bf(v.x); p.y = f2bf(v.y); p.z = f2bf(v.z); p.w = f2bf(v.w);
      *(ushort4*)(Qs + swz(r, c * 2)) = p;
    }
  }
  __syncthreads();
  const s16x8 qa0 = *(const s16x8*)(Qs + swz(wv * 16 + l15, g4 * 16));
  const s16x8 qa1 = *(const s16x8*)(Qs + swz(wv * 16 + l15, g4 * 16 + 64));

  f32x4 oacc[4];
#pragma unroll
  for (int i = 0; i < 4; ++i) oacc[i] = f32x4{0.f, 0.f, 0.f, 0.f};
  float lp[4] = {0.f, 0.f, 0.f, 0.f};

  const int qrow = wv * 16 + g4 * 4;

  // ================= PASS 1: rowsum + O accumulate =================
  for (int kt = 0; kt < NT; ++kt) {
    __syncthreads();
    {
      const int r0 = tid >> 4;
      const int c  = (tid & 15) * 4;
      // K: f32 -> bf16 staged, ~2-way (free) bank pattern
      const float* Kt = Kg + kt * 64 * D_DIM;
#pragma unroll
      for (int i = 0; i < 4; ++i) {
        const int r = r0 + i * 16;
        float4 v = *(const float4*)(Kt + r * D_DIM + c);
        ushort4 p; p.x = f2bf(v.x); p.y = f2bf(v.y); p.z = f2bf(v.z); p.w = f2bf(v.w);
        *(ushort4*)(Ks + swz(r, c * 2)) = p;
      }
      // V: copy rows of pre-transposed VT (d-major) — same pattern as K,
      // conflict-free (replaces the 8-way-conflicted in-kernel transpose)
#pragma unroll
      for (int i = 0; i < 4; ++i) {
        const int r = r0 + i * 16;   // d
        ushort4 v = *(const ushort4*)(Vg + (size_t)r * S_LEN + kt * 64 + c);
        *(ushort4*)(VTs + swz(r, c * 2)) = v;
      }
    }
    __syncthreads();

    unsigned long long mw[4];
#pragma unroll
    for (int r = 0; r < 4; ++r) mw[r] = Mg[(qrow + r) * SW + kt];

    f32x4 sacc[4];
#pragma unroll
    for (int i = 0; i < 4; ++i) sacc[i] = f32x4{0.f, 0.f, 0.f, 0.f};
#pragma unroll
    for (int ct = 0; ct < 4; ++ct) {
      s16x8 b0 = *(const s16x8*)(Ks + swz(ct * 16 + l15, g4 * 16));
      s16x8 b1 = *(const s16x8*)(Ks + swz(ct * 16 + l15, g4 * 16 + 64));
      sacc[ct] = mfma16(sacc[ct], qa0, b0);
      sacc[ct] = mfma16(sacc[ct], qa1, b1);
    }

#pragma unroll
    for (int ct = 0; ct < 4; ++ct) {
#pragma unroll
      for (int r = 0; r < 4; ++r) {
        float e = __expf(sacc[ct][r] * 0.125f);
        e = ((mw[r] >> (ct * 16 + l15)) & 1ull) ? e : 0.f;
        lp[r] += e;
        *(unsigned short*)(Ps + swz(g4 * 4 + r, (ct * 16 + l15) * 2)) = f2bf(e);
      }
    }
    // wave-internal cross-lane LDS hazard: drain DS queue, pin reads after
    asm volatile("s_waitcnt lgkmcnt(0)" ::: "memory");
    __builtin_amdgcn_sched_barrier(0);

    const s16x8 pa0 = *(const s16x8*)(Ps + swz(l15, g4 * 16));
    const s16x8 pa1 = *(const s16x8*)(Ps + swz(l15, g4 * 16 + 64));
#pragma unroll
    for (int ct = 0; ct < 4; ++ct) {
      s16x8 v0 = *(const s16x8*)(VTs + swz(ct * 16 + l15, g4 * 16));
      s16x8 v1 = *(const s16x8*)(VTs + swz(ct * 16 + l15, g4 * 16 + 64));
      oacc[ct] = mfma16(oacc[ct], pa0, v0);
      oacc[ct] = mfma16(oacc[ct], pa1, v1);
    }
  }

  // rowsum reduce across the 16-lane column group; keep reciprocal
#pragma unroll
  for (int r = 0; r < 4; ++r) {
    float v = lp[r];
    v += __shfl_xor(v, 1);
    v += __shfl_xor(v, 2);
    v += __shfl_xor(v, 4);
    v += __shfl_xor(v, 8);
    lp[r] = 1.0f / v;
  }

#pragma unroll
  for (int ct = 0; ct < 4; ++ct)
#pragma unroll
    for (int r = 0; r < 4; ++r)
      Og[(size_t)(qrow + r) * D_DIM + ct * 16 + l15] = oacc[ct][r] * lp[r];

  // keep pass-2 loads from being hoisted into pass 1 (VGPR pressure)
  __builtin_amdgcn_sched_barrier(0);

  // ===== PASS 2: recompute scores from global bf16 K, stream weights =====
  // No LDS, no barriers: the 537MB NT-store stream runs free.
  s16x8 kb0[4], kb1[4];
#pragma unroll
  for (int ct = 0; ct < 4; ++ct) {
    const unsigned short* kp = Kg16 + (size_t)(ct * 16 + l15) * D_DIM + g4 * 8;
    kb0[ct] = *(const s16x8*)kp;
    kb1[ct] = *(const s16x8*)(kp + 32);
  }

  for (int kt = 0; kt < NT; ++kt) {
    const int ktn = (kt < NT - 1) ? kt + 1 : kt;
    s16x8 nk0[4], nk1[4];
#pragma unroll
    for (int ct = 0; ct < 4; ++ct) {
      const unsigned short* kp = Kg16 + (size_t)(ktn * 64 + ct * 16 + l15) * D_DIM + g4 * 8;
      nk0[ct] = *(const s16x8*)kp;
      nk1[ct] = *(const s16x8*)(kp + 32);
    }

    unsigned long long mw[4];
#pragma unroll
    for (int r = 0; r < 4; ++r) mw[r] = Mg[(qrow + r) * SW + kt];

    f32x4 sacc[4];
#pragma unroll
    for (int i = 0; i < 4; ++i) sacc[i] = f32x4{0.f, 0.f, 0.f, 0.f};
#pragma unroll
    for (int ct = 0; ct < 4; ++ct) {
      sacc[ct] = mfma16(sacc[ct], qa0, kb0[ct]);
      sacc[ct] = mfma16(sacc[ct], qa1, kb1[ct]);
    }

#pragma unroll
    for (int ct = 0; ct < 4; ++ct) {
#pragma unroll
      for (int r = 0; r < 4; ++r) {
        float e = __expf(sacc[ct][r] * 0.125f);
        e = ((mw[r] >> (ct * 16 + l15)) & 1ull) ? e * lp[r] : 0.f;
        __builtin_nontemporal_store(e,
            Wg + (size_t)(qrow + r) * S_LEN + kt * 64 + ct * 16 + l15);
      }
    }
#pragma unroll
    for (int ct = 0; ct < 4; ++ct) { kb0[ct] = nk0[ct]; kb1[ct] = nk1[ct]; }
  }
}

// ---------------- fallback (round-1 kernel, fp32 inputs, LDS-staged) ----------------

template <int USE_BITS>
__global__ __launch_bounds__(256) void attn_fwd_kernel(
    const float* __restrict__ Qp, const float* __restrict__ Kp, const float* __restrict__ Vp,
    const unsigned long long* __restrict__ Mb, const int* __restrict__ Mi,
    float* __restrict__ Op, float* __restrict__ Wp)
{
  const int tid  = threadIdx.x;
  const int lane = tid & 63;
  const int wv   = tid >> 6;
  const int l15  = lane & 15;
  const int g4   = lane >> 4;

  const int wg = blockIdx.x;
  const int lg = (wg & 7) * 128 + (wg >> 3);
  const int qt = lg & 31;
  const int bh = lg >> 5;
  const int b  = bh >> 4;

  __shared__ __align__(16) char lds[32768];
  char* Qs  = lds;
  char* Ks  = lds + 8192;
  char* VTs = lds + 16384;
  char* Ps  = lds + 24576 + (wv << 11);

  const float* Qg = Qp + ((size_t)bh * S_LEN + qt * 64) * D_DIM;
  const float* Kg = Kp + (size_t)bh * S_LEN * D_DIM;
  const float* Vg = Vp + (size_t)bh * S_LEN * D_DIM;
  float* Og = Op + ((size_t)bh * S_LEN + qt * 64) * D_DIM;
  float* Wg = Wp + ((size_t)bh * S_LEN + qt * 64) * S_LEN;
  const unsigned long long* Mg = Mb + ((size_t)b * S_LEN + qt * 64) * SW;
  const int* Mig = Mi + ((size_t)b * S_LEN + qt * 64) * S_LEN;

  {
    const int r0 = tid >> 4;
    const int c  = (tid & 15) * 4;
#pragma unroll
    for (int i = 0; i < 4; ++i) {
      const int r = r0 + i * 16;
      float4 v = *(const float4*)(Qg + r * D_DIM + c);
      ushort4 p; p.x = f2bf(v.x); p.y = f2bf(v.y); p.z = f2bf(v.z); p.w = f2bf(v.w);
      *(ushort4*)(Qs + swz(r, c * 2)) = p;
    }
  }
  __syncthreads();
  const s16x8 qa0 = *(const s16x8*)(Qs + swz(wv * 16 + l15, g4 * 16));
  const s16x8 qa1 = *(const s16x8*)(Qs + swz(wv * 16 + l15, g4 * 16 + 64));

  f32x4 oacc[4];
#pragma unroll
  for (int i = 0; i < 4; ++i) oacc[i] = f32x4{0.f, 0.f, 0.f, 0.f};
  float lp[4] = {0.f, 0.f, 0.f, 0.f};

  const int qrow = wv * 16 + g4 * 4;

  for (int kt = 0; kt < NT; ++kt) {
    __syncthreads();
    {
      const int r0 = tid >> 4;
      const int c  = (tid & 15) * 4;
      const float* Kt = Kg + kt * 64 * D_DIM;
#pragma unroll
      for (int i = 0; i < 4; ++i) {
        const int r = r0 + i * 16;
        float4 v = *(const float4*)(Kt + r * D_DIM + c);
        ushort4 p; p.x = f2bf(v.x); p.y = f2bf(v.y); p.z = f2bf(v.z); p.w = f2bf(v.w);
        *(ushort4*)(Ks + swz(r, c * 2)) = p;
      }
      const float* Vt = Vg + kt * 64 * D_DIM;
#pragma unroll
      for (int i = 0; i < 2; ++i) {
        const int rr = (tid >> 4) * 2 + i * 32;
        float4 a  = *(const float4*)(Vt + rr * D_DIM + c);
        float4 bq = *(const float4*)(Vt + (rr + 1) * D_DIM + c);
        const float av[4] = {a.x, a.y, a.z, a.w};
        const float bv[4] = {bq.x, bq.y, bq.z, bq.w};
#pragma unroll
        for (int j = 0; j < 4; ++j) {
          unsigned pk = (unsigned)f2bf(av[j]) | ((unsigned)f2bf(bv[j]) << 16);
          *(unsigned*)(VTs + swz(c + j, rr * 2)) = pk;
        }
      }
    }
    __syncthreads();

    unsigned long long mw[4] = {0, 0, 0, 0};
    if (USE_BITS) {
#pragma unroll
      for (int r = 0; r < 4; ++r) mw[r] = Mg[(qrow + r) * SW + kt];
    }

    f32x4 sacc[4];
#pragma unroll
    for (int i = 0; i < 4; ++i) sacc[i] = f32x4{0.f, 0.f, 0.f, 0.f};
#pragma unroll
    for (int ct = 0; ct < 4; ++ct) {
      s16x8 b0 = *(const s16x8*)(Ks + swz(ct * 16 + l15, g4 * 16));
      s16x8 b1 = *(const s16x8*)(Ks + swz(ct * 16 + l15, g4 * 16 + 64));
      sacc[ct] = mfma16(sacc[ct], qa0, b0);
      sacc[ct] = mfma16(sacc[ct], qa1, b1);
    }

#pragma unroll
    for (int ct = 0; ct < 4; ++ct) {
#pragma unroll
      for (int r = 0; r < 4; ++r) {
        float e = __expf(sacc[ct][r] * 0.125f);
        bool keep;
        if (USE_BITS) keep = (mw[r] >> (ct * 16 + l15)) & 1ull;
        else          keep = Mig[(size_t)(qrow + r) * S_LEN + kt * 64 + ct * 16 + l15] != 0;
        e = keep ? e : 0.f;
        lp[r] += e;
        *(unsigned short*)(Ps + swz(g4 * 4 + r, (ct * 16 + l15) * 2)) = f2bf(e);
      }
    }
    asm volatile("s_waitcnt lgkmcnt(0)" ::: "memory");
    __builtin_amdgcn_sched_barrier(0);

    const s16x8 pa0 = *(const s16x8*)(Ps + swz(l15, g4 * 16));
    const s16x8 pa1 = *(const s16x8*)(Ps + swz(l15, g4 * 16 + 64));
#pragma unroll
    for (int ct = 0; ct < 4; ++ct) {
      s16x8 v0 = *(const s16x8*)(VTs + swz(ct * 16 + l15, g4 * 16));
      s16x8 v1 = *(const s16x8*)(VTs + swz(ct * 16 + l15, g4 * 16 + 64));
      oacc[ct] = mfma16(oacc[ct], pa0, v0);
      oacc[ct] = mfma16(oacc[ct], pa1, v1);
    }
  }

#pragma unroll
  for (int r = 0; r < 4; ++r) {
    float v = lp[r];
    v += __shfl_xor(v, 1);
    v += __shfl_xor(v, 2);
    v += __shfl_xor(v, 4);
    v += __shfl_xor(v, 8);
    lp[r] = 1.0f / v;
  }

#pragma unroll
  for (int ct = 0; ct < 4; ++ct)
#pragma unroll
    for (int r = 0; r < 4; ++r)
      Og[(size_t)(qrow + r) * D_DIM + ct * 16 + l15] = oacc[ct][r] * lp[r];

  for (int kt = 0; kt < NT; ++kt) {
    __syncthreads();
    {
      const int r0 = tid >> 4;
      const int c  = (tid & 15) * 4;
      const float* Kt = Kg + kt * 64 * D_DIM;
#pragma unroll
      for (int i = 0; i < 4; ++i) {
        const int r = r0 + i * 16;
        float4 v = *(const float4*)(Kt + r * D_DIM + c);
        ushort4 p; p.x = f2bf(v.x); p.y = f2bf(v.y); p.z = f2bf(v.z); p.w = f2bf(v.w);
        *(ushort4*)(Ks + swz(r, c * 2)) = p;
      }
    }
    __syncthreads();

    unsigned long long mw[4] = {0, 0, 0, 0};
    if (USE_BITS) {
#pragma unroll
      for (int r = 0; r < 4; ++r) mw[r] = Mg[(qrow + r) * SW + kt];
    }

    f32x4 sacc[4];
#pragma unroll
    for (int i = 0; i < 4; ++i) sacc[i] = f32x4{0.f, 0.f, 0.f, 0.f};
#pragma unroll
    for (int ct = 0; ct < 4; ++ct) {
      s16x8 b0 = *(const s16x8*)(Ks + swz(ct * 16 + l15, g4 * 16));
      s16x8 b1 = *(const s16x8*)(Ks + swz(ct * 16 + l15, g4 * 16 + 64));
      sacc[ct] = mfma16(sacc[ct], qa0, b0);
      sacc[ct] = mfma16(sacc[ct], qa1, b1);
    }

#pragma unroll
    for (int ct = 0; ct < 4; ++ct) {
#pragma unroll
      for (int r = 0; r < 4; ++r) {
        float e = __expf(sacc[ct][r] * 0.125f);
        bool keep;
        if (USE_BITS) keep = (mw[r] >> (ct * 16 + l15)) & 1ull;
        else          keep = Mig[(size_t)(qrow + r) * S_LEN + kt * 64 + ct * 16 + l15] != 0;
        e = keep ? e : 0.f;
        __builtin_nontemporal_store(e * lp[r],
            Wg + (size_t)(qrow + r) * S_LEN + kt * 64 + ct * 16 + l15);
      }
    }
  }
}

extern "C" void kernel_launch(void* const* d_in, const int* in_sizes, int n_in,
                              void* d_out, int out_size, void* d_ws, size_t ws_size,
                              hipStream_t stream) {
  (void)in_sizes; (void)n_in; (void)out_size;
  const float* Q   = (const float*)d_in[0];
  const float* K   = (const float*)d_in[1];
  const float* V   = (const float*)d_in[2];
  const int* mask  = (const int*)d_in[3];
  float* Out = (float*)d_out;
  float* W   = Out + (size_t)B_NUM * H_NUM * S_LEN * D_DIM;

  const size_t bits_bytes = (size_t)(B_NUM * S_LEN * S_LEN / 64) * 8;      // 1 MiB
  const size_t t16_bytes  = (size_t)B_NUM * H_NUM * S_LEN * D_DIM * 2;     // 8 MiB
  unsigned long long* bits = (unsigned long long*)d_ws;

  if (ws_size >= bits_bytes + 2 * t16_bytes) {
    unsigned short* K16 = (unsigned short*)((char*)d_ws + bits_bytes);
    unsigned short* VT  = K16 + t16_bytes / 2;
    mask_pack_kernel<<<1024, 256, 0, stream>>>(mask, bits);
    cvt_k_kernel<<<1024, 256, 0, stream>>>(K, (u16x4*)K16);
    v_transpose_kernel<<<1024, 256, 0, stream>>>(V, VT);
    attn_fused_kernel<<<1024, 256, 0, stream>>>(Q, K, K16, VT, bits, Out, W);
  } else if (ws_size >= bits_bytes) {
    mask_pack_kernel<<<1024, 256, 0, stream>>>(mask, bits);
    attn_fwd_kernel<1><<<1024, 256, 0, stream>>>(Q, K, V, bits, mask, Out, W);
  } else {
    attn_fwd_kernel<0><<<1024, 256, 0, stream>>>(Q, K, V, bits, mask, Out, W);
  }
}

// Round 7
// 252.645 us; speedup vs baseline: 1.8535x; 1.0544x over previous
//
#include <hip/hip_runtime.h>

// ScaledDotProductAttention fwd: out0 = attn output [2,16,2048,64] f32,
// out1 = attn weights [2,16,2048,2048] f32.
// Round 7: pass-1 latency attack with proven primitives.
//  - All staging from pre-converted bf16 (Q16/K16/VT16 prep): no f2bf in the
//    main loop's staging path.
//  - T14 async-STAGE split, double-buffered: loads for tile kt+1 issued
//    BEFORE compute of tile kt; ds_writes after (vmcnt wait = data dep, ~free);
//    one __syncthreads per iter. Staging latency hides under compute.
//  - 1/sqrt(dk)=0.125 folded into Q16 (exponent-exact in bf16): kills the
//    scale mul in both passes' exp sections.
//  - Ps single-buffered (wave-private, DS FIFO ordering) -> LDS 40KB, 4 blk/CU.
// Pass 2 unchanged from round 6 (barrier-free weight stream, validated).

typedef __attribute__((ext_vector_type(4))) float f32x4;
typedef __attribute__((ext_vector_type(8))) short s16x8;
typedef __attribute__((ext_vector_type(4))) unsigned short u16x4;
typedef __attribute__((ext_vector_type(8))) unsigned short u16x8;

#define S_LEN 2048
#define D_DIM 64
#define H_NUM 16
#define B_NUM 2
#define NT    32   // S/64 k-tiles
#define SW    32   // mask words per row (S/64)

__device__ __forceinline__ int swz(int row, int colByte) {
  return row * 128 + (colByte ^ ((row & 7) << 4));
}

__device__ __forceinline__ unsigned short f2bf(float f) {  // RNE f32->bf16
  unsigned int x = __builtin_bit_cast(unsigned int, f);
  x = (x + 0x7FFFu + ((x >> 16) & 1u)) >> 16;
  return (unsigned short)x;
}

__device__ __forceinline__ f32x4 mfma16(f32x4 acc, s16x8 a, s16x8 b) {
  return __builtin_amdgcn_mfma_f32_16x16x32_bf16(a, b, acc, 0, 0, 0);
}

// ---------------- prep kernels ----------------

__global__ __launch_bounds__(256) void mask_pack_kernel(const int* __restrict__ m,
                                                        unsigned long long* __restrict__ bits) {
  const int total = B_NUM * S_LEN * S_LEN;
  const int step  = gridDim.x * blockDim.x;
  for (int i = blockIdx.x * blockDim.x + threadIdx.x; i < total; i += step) {
    unsigned long long b = __ballot(m[i] != 0);
    if ((threadIdx.x & 63) == 0) bits[i >> 6] = b;
  }
}

// Q scaled by 0.125 (exact exponent shift in bf16); K unscaled.
__global__ __launch_bounds__(256) void cvt_qk_kernel(const float* __restrict__ Q,
                                                     const float* __restrict__ K,
                                                     u16x4* __restrict__ Q16,
                                                     u16x4* __restrict__ K16) {
  const int n4 = B_NUM * H_NUM * S_LEN * D_DIM / 4;
  const int step = gridDim.x * blockDim.x;
  for (int i = blockIdx.x * blockDim.x + threadIdx.x; i < n4; i += step) {
    float4 q = ((const float4*)Q)[i];
    Q16[i] = u16x4{f2bf(q.x * 0.125f), f2bf(q.y * 0.125f),
                   f2bf(q.z * 0.125f), f2bf(q.w * 0.125f)};
    float4 k = ((const float4*)K)[i];
    K16[i] = u16x4{f2bf(k.x), f2bf(k.y), f2bf(k.z), f2bf(k.w)};
  }
}

__global__ __launch_bounds__(256) void v_transpose_kernel(const float* __restrict__ V,
                                                          unsigned short* __restrict__ VT) {
  __shared__ unsigned short t[64][72];
  const int bh = blockIdx.x >> 5;   // grid 1024
  const int st = blockIdx.x & 31;
  const float* src = V + ((size_t)bh * S_LEN + st * 64) * D_DIM;
  const int r0 = threadIdx.x >> 4;
  const int c  = (threadIdx.x & 15) * 4;
#pragma unroll
  for (int i = 0; i < 4; ++i) {
    const int r = r0 + i * 16;
    float4 v = *(const float4*)(src + r * D_DIM + c);
    t[c + 0][r] = f2bf(v.x); t[c + 1][r] = f2bf(v.y);
    t[c + 2][r] = f2bf(v.z); t[c + 3][r] = f2bf(v.w);
  }
  __syncthreads();
#pragma unroll
  for (int i = 0; i < 4; ++i) {
    const int idx = threadIdx.x + i * 256;
    const int d = idx >> 4;
    const int s4 = (idx & 15) * 4;
    u16x4 o = {t[d][s4], t[d][s4 + 1], t[d][s4 + 2], t[d][s4 + 3]};
    *(u16x4*)(VT + ((size_t)bh * D_DIM + d) * S_LEN + st * 64 + s4) = o;
  }
}

// ---------------- fused main kernel ----------------

__global__ __launch_bounds__(256) void attn_fused_kernel(
    const unsigned short* __restrict__ Q16, const unsigned short* __restrict__ K16,
    const unsigned short* __restrict__ VT16, const unsigned long long* __restrict__ Mb,
    float* __restrict__ Op, float* __restrict__ Wp)
{
  const int tid  = threadIdx.x;
  const int lane = tid & 63;
  const int wv   = tid >> 6;
  const int l15  = lane & 15;
  const int g4   = lane >> 4;

  const int wg = blockIdx.x;                 // 1024 blocks
  const int lg = (wg & 7) * 128 + (wg >> 3); // bijective XCD swizzle
  const int qt = lg & 31;
  const int bh = lg >> 5;
  const int b  = bh >> 4;

  __shared__ __align__(16) char lds[40960];
  char* Kbuf = lds;                          // 2 x [64 k][64 d] bf16 swz
  char* Vbuf = lds + 16384;                  // 2 x [64 d][64 s] bf16 swz
  char* Ps   = lds + 32768 + (wv << 11);     // per-wave [16][64] bf16 swz

  const unsigned short* Qg16 = Q16 + ((size_t)bh * S_LEN + qt * 64 + wv * 16 + l15) * D_DIM + g4 * 8;
  const unsigned short* Kg16 = K16 + (size_t)bh * S_LEN * D_DIM;
  const unsigned short* Vg   = VT16 + (size_t)bh * D_DIM * S_LEN;
  float* Og = Op + ((size_t)bh * S_LEN + qt * 64) * D_DIM;
  float* Wg = Wp + ((size_t)bh * S_LEN + qt * 64) * S_LEN;
  const unsigned long long* Mg = Mb + ((size_t)b * S_LEN + qt * 64) * SW;

  // Q frags direct from global bf16 (validated round 3)
  const s16x8 qa0 = *(const s16x8*)Qg16;
  const s16x8 qa1 = *(const s16x8*)(Qg16 + 32);

  f32x4 oacc[4];
#pragma unroll
  for (int i = 0; i < 4; ++i) oacc[i] = f32x4{0.f, 0.f, 0.f, 0.f};
  float lp[4] = {0.f, 0.f, 0.f, 0.f};

  const int qrow = wv * 16 + g4 * 4;

  // staging geometry: thread -> rows {sr, sr+32}, 16B slot ss
  const int sr  = tid >> 3;   // 0..31
  const int ss  = tid & 7;    // 16B slot index
  const int ssb = ss * 16;    // byte offset within row

  // ---- prologue: stage tile 0 into buffer 0 ----
  {
    u16x8 k0 = *(const u16x8*)(Kg16 + (size_t)sr * D_DIM + ss * 8);
    u16x8 k1 = *(const u16x8*)(Kg16 + (size_t)(sr + 32) * D_DIM + ss * 8);
    u16x8 v0 = *(const u16x8*)(Vg + (size_t)sr * S_LEN + ss * 8);
    u16x8 v1 = *(const u16x8*)(Vg + (size_t)(sr + 32) * S_LEN + ss * 8);
    *(u16x8*)(Kbuf + swz(sr, ssb))      = k0;
    *(u16x8*)(Kbuf + swz(sr + 32, ssb)) = k1;
    *(u16x8*)(Vbuf + swz(sr, ssb))      = v0;
    *(u16x8*)(Vbuf + swz(sr + 32, ssb)) = v1;
  }
  __syncthreads();

  // ================= PASS 1: rowsum + O accumulate =================
  int cur = 0;
  for (int kt = 0; kt < NT; ++kt) {
    // issue next-tile loads FIRST (fly during compute)
    const int ktn = (kt + 1 < NT) ? kt + 1 : kt;
    u16x8 kr0 = *(const u16x8*)(Kg16 + (size_t)(ktn * 64 + sr) * D_DIM + ss * 8);
    u16x8 kr1 = *(const u16x8*)(Kg16 + (size_t)(ktn * 64 + sr + 32) * D_DIM + ss * 8);
    u16x8 vr0 = *(const u16x8*)(Vg + (size_t)sr * S_LEN + ktn * 64 + ss * 8);
    u16x8 vr1 = *(const u16x8*)(Vg + (size_t)(sr + 32) * S_LEN + ktn * 64 + ss * 8);
    __builtin_amdgcn_sched_barrier(0);   // pin load issue above compute

    char* Kc = Kbuf + cur * 8192;
    char* Vc = Vbuf + cur * 8192;

    unsigned long long mw[4];
#pragma unroll
    for (int r = 0; r < 4; ++r) mw[r] = Mg[(qrow + r) * SW + kt];

    f32x4 sacc[4];
#pragma unroll
    for (int i = 0; i < 4; ++i) sacc[i] = f32x4{0.f, 0.f, 0.f, 0.f};
#pragma unroll
    for (int ct = 0; ct < 4; ++ct) {
      s16x8 b0 = *(const s16x8*)(Kc + swz(ct * 16 + l15, g4 * 16));
      s16x8 b1 = *(const s16x8*)(Kc + swz(ct * 16 + l15, g4 * 16 + 64));
      sacc[ct] = mfma16(sacc[ct], qa0, b0);
      sacc[ct] = mfma16(sacc[ct], qa1, b1);
    }

#pragma unroll
    for (int ct = 0; ct < 4; ++ct) {
#pragma unroll
      for (int r = 0; r < 4; ++r) {
        float e = __expf(sacc[ct][r]);    // scale pre-folded into Q16
        e = ((mw[r] >> (ct * 16 + l15)) & 1ull) ? e : 0.f;
        lp[r] += e;
        *(unsigned short*)(Ps + swz(g4 * 4 + r, (ct * 16 + l15) * 2)) = f2bf(e);
      }
    }
    // wave-internal cross-lane LDS hazard: drain DS queue, pin reads after
    asm volatile("s_waitcnt lgkmcnt(0)" ::: "memory");
    __builtin_amdgcn_sched_barrier(0);

    const s16x8 pa0 = *(const s16x8*)(Ps + swz(l15, g4 * 16));
    const s16x8 pa1 = *(const s16x8*)(Ps + swz(l15, g4 * 16 + 64));
#pragma unroll
    for (int ct = 0; ct < 4; ++ct) {
      s16x8 v0 = *(const s16x8*)(Vc + swz(ct * 16 + l15, g4 * 16));
      s16x8 v1 = *(const s16x8*)(Vc + swz(ct * 16 + l15, g4 * 16 + 64));
      oacc[ct] = mfma16(oacc[ct], pa0, v0);
      oacc[ct] = mfma16(oacc[ct], pa1, v1);
    }

    // write staged regs -> other buffer (vmcnt wait = data dep, loads long done)
    char* Kn = Kbuf + (cur ^ 1) * 8192;
    char* Vn = Vbuf + (cur ^ 1) * 8192;
    *(u16x8*)(Kn + swz(sr, ssb))      = kr0;
    *(u16x8*)(Kn + swz(sr + 32, ssb)) = kr1;
    *(u16x8*)(Vn + swz(sr, ssb))      = vr0;
    *(u16x8*)(Vn + swz(sr + 32, ssb)) = vr1;
    __syncthreads();
    cur ^= 1;
  }

  // rowsum reduce across the 16-lane column group; keep reciprocal
#pragma unroll
  for (int r = 0; r < 4; ++r) {
    float v = lp[r];
    v += __shfl_xor(v, 1);
    v += __shfl_xor(v, 2);
    v += __shfl_xor(v, 4);
    v += __shfl_xor(v, 8);
    lp[r] = 1.0f / v;
  }

#pragma unroll
  for (int ct = 0; ct < 4; ++ct)
#pragma unroll
    for (int r = 0; r < 4; ++r)
      Og[(size_t)(qrow + r) * D_DIM + ct * 16 + l15] = oacc[ct][r] * lp[r];

  // keep pass-2 loads from hoisting into pass 1 (VGPR pressure)
  __builtin_amdgcn_sched_barrier(0);

  // ===== PASS 2: recompute scores from global bf16 K, stream weights =====
  s16x8 kb0[4], kb1[4];
#pragma unroll
  for (int ct = 0; ct < 4; ++ct) {
    const unsigned short* kp = Kg16 + (size_t)(ct * 16 + l15) * D_DIM + g4 * 8;
    kb0[ct] = *(const s16x8*)kp;
    kb1[ct] = *(const s16x8*)(kp + 32);
  }

  for (int kt = 0; kt < NT; ++kt) {
    const int ktn = (kt < NT - 1) ? kt + 1 : kt;
    s16x8 nk0[4], nk1[4];
#pragma unroll
    for (int ct = 0; ct < 4; ++ct) {
      const unsigned short* kp = Kg16 + (size_t)(ktn * 64 + ct * 16 + l15) * D_DIM + g4 * 8;
      nk0[ct] = *(const s16x8*)kp;
      nk1[ct] = *(const s16x8*)(kp + 32);
    }

    unsigned long long mw[4];
#pragma unroll
    for (int r = 0; r < 4; ++r) mw[r] = Mg[(qrow + r) * SW + kt];

    f32x4 sacc[4];
#pragma unroll
    for (int i = 0; i < 4; ++i) sacc[i] = f32x4{0.f, 0.f, 0.f, 0.f};
#pragma unroll
    for (int ct = 0; ct < 4; ++ct) {
      sacc[ct] = mfma16(sacc[ct], qa0, kb0[ct]);
      sacc[ct] = mfma16(sacc[ct], qa1, kb1[ct]);
    }

#pragma unroll
    for (int ct = 0; ct < 4; ++ct) {
#pragma unroll
      for (int r = 0; r < 4; ++r) {
        float e = __expf(sacc[ct][r]);
        e = ((mw[r] >> (ct * 16 + l15)) & 1ull) ? e * lp[r] : 0.f;
        __builtin_nontemporal_store(e,
            Wg + (size_t)(qrow + r) * S_LEN + kt * 64 + ct * 16 + l15);
      }
    }
#pragma unroll
    for (int ct = 0; ct < 4; ++ct) { kb0[ct] = nk0[ct]; kb1[ct] = nk1[ct]; }
  }
}

// ---------------- fallback (fp32 inputs, LDS-staged) ----------------

template <int USE_BITS>
__global__ __launch_bounds__(256) void attn_fwd_kernel(
    const float* __restrict__ Qp, const float* __restrict__ Kp, const float* __restrict__ Vp,
    const unsigned long long* __restrict__ Mb, const int* __restrict__ Mi,
    float* __restrict__ Op, float* __restrict__ Wp)
{
  const int tid  = threadIdx.x;
  const int lane = tid & 63;
  const int wv   = tid >> 6;
  const int l15  = lane & 15;
  const int g4   = lane >> 4;

  const int wg = blockIdx.x;
  const int lg = (wg & 7) * 128 + (wg >> 3);
  const int qt = lg & 31;
  const int bh = lg >> 5;
  const int b  = bh >> 4;

  __shared__ __align__(16) char lds[32768];
  char* Qs  = lds;
  char* Ks  = lds + 8192;
  char* VTs = lds + 16384;
  char* Ps  = lds + 24576 + (wv << 11);

  const float* Qg = Qp + ((size_t)bh * S_LEN + qt * 64) * D_DIM;
  const float* Kg = Kp + (size_t)bh * S_LEN * D_DIM;
  const float* Vg = Vp + (size_t)bh * S_LEN * D_DIM;
  float* Og = Op + ((size_t)bh * S_LEN + qt * 64) * D_DIM;
  float* Wg = Wp + ((size_t)bh * S_LEN + qt * 64) * S_LEN;
  const unsigned long long* Mg = Mb + ((size_t)b * S_LEN + qt * 64) * SW;
  const int* Mig = Mi + ((size_t)b * S_LEN + qt * 64) * S_LEN;

  {
    const int r0 = tid >> 4;
    const int c  = (tid & 15) * 4;
#pragma unroll
    for (int i = 0; i < 4; ++i) {
      const int r = r0 + i * 16;
      float4 v = *(const float4*)(Qg + r * D_DIM + c);
      ushort4 p; p.x = f2bf(v.x); p.y = f2bf(v.y); p.z = f2bf(v.z); p.w = f2bf(v.w);
      *(ushort4*)(Qs + swz(r, c * 2)) = p;
    }
  }
  __syncthreads();
  const s16x8 qa0 = *(const s16x8*)(Qs + swz(wv * 16 + l15, g4 * 16));
  const s16x8 qa1 = *(const s16x8*)(Qs + swz(wv * 16 + l15, g4 * 16 + 64));

  f32x4 oacc[4];
#pragma unroll
  for (int i = 0; i < 4; ++i) oacc[i] = f32x4{0.f, 0.f, 0.f, 0.f};
  float lp[4] = {0.f, 0.f, 0.f, 0.f};

  const int qrow = wv * 16 + g4 * 4;

  for (int kt = 0; kt < NT; ++kt) {
    __syncthreads();
    {
      const int r0 = tid >> 4;
      const int c  = (tid & 15) * 4;
      const float* Kt = Kg + kt * 64 * D_DIM;
#pragma unroll
      for (int i = 0; i < 4; ++i) {
        const int r = r0 + i * 16;
        float4 v = *(const float4*)(Kt + r * D_DIM + c);
        ushort4 p; p.x = f2bf(v.x); p.y = f2bf(v.y); p.z = f2bf(v.z); p.w = f2bf(v.w);
        *(ushort4*)(Ks + swz(r, c * 2)) = p;
      }
      const float* Vt = Vg + kt * 64 * D_DIM;
#pragma unroll
      for (int i = 0; i < 2; ++i) {
        const int rr = (tid >> 4) * 2 + i * 32;
        float4 a  = *(const float4*)(Vt + rr * D_DIM + c);
        float4 bq = *(const float4*)(Vt + (rr + 1) * D_DIM + c);
        const float av[4] = {a.x, a.y, a.z, a.w};
        const float bv[4] = {bq.x, bq.y, bq.z, bq.w};
#pragma unroll
        for (int j = 0; j < 4; ++j) {
          unsigned pk = (unsigned)f2bf(av[j]) | ((unsigned)f2bf(bv[j]) << 16);
          *(unsigned*)(VTs + swz(c + j, rr * 2)) = pk;
        }
      }
    }
    __syncthreads();

    unsigned long long mw[4] = {0, 0, 0, 0};
    if (USE_BITS) {
#pragma unroll
      for (int r = 0; r < 4; ++r) mw[r] = Mg[(qrow + r) * SW + kt];
    }

    f32x4 sacc[4];
#pragma unroll
    for (int i = 0; i < 4; ++i) sacc[i] = f32x4{0.f, 0.f, 0.f, 0.f};
#pragma unroll
    for (int ct = 0; ct < 4; ++ct) {
      s16x8 b0 = *(const s16x8*)(Ks + swz(ct * 16 + l15, g4 * 16));
      s16x8 b1 = *(const s16x8*)(Ks + swz(ct * 16 + l15, g4 * 16 + 64));
      sacc[ct] = mfma16(sacc[ct], qa0, b0);
      sacc[ct] = mfma16(sacc[ct], qa1, b1);
    }

#pragma unroll
    for (int ct = 0; ct < 4; ++ct) {
#pragma unroll
      for (int r = 0; r < 4; ++r) {
        float e = __expf(sacc[ct][r] * 0.125f);
        bool keep;
        if (USE_BITS) keep = (mw[r] >> (ct * 16 + l15)) & 1ull;
        else          keep = Mig[(size_t)(qrow + r) * S_LEN + kt * 64 + ct * 16 + l15] != 0;
        e = keep ? e : 0.f;
        lp[r] += e;
        *(unsigned short*)(Ps + swz(g4 * 4 + r, (ct * 16 + l15) * 2)) = f2bf(e);
      }
    }
    asm volatile("s_waitcnt lgkmcnt(0)" ::: "memory");
    __builtin_amdgcn_sched_barrier(0);

    const s16x8 pa0 = *(const s16x8*)(Ps + swz(l15, g4 * 16));
    const s16x8 pa1 = *(const s16x8*)(Ps + swz(l15, g4 * 16 + 64));
#pragma unroll
    for (int ct = 0; ct < 4; ++ct) {
      s16x8 v0 = *(const s16x8*)(VTs + swz(ct * 16 + l15, g4 * 16));
      s16x8 v1 = *(const s16x8*)(VTs + swz(ct * 16 + l15, g4 * 16 + 64));
      oacc[ct] = mfma16(oacc[ct], pa0, v0);
      oacc[ct] = mfma16(oacc[ct], pa1, v1);
    }
  }

#pragma unroll
  for (int r = 0; r < 4; ++r) {
    float v = lp[r];
    v += __shfl_xor(v, 1);
    v += __shfl_xor(v, 2);
    v += __shfl_xor(v, 4);
    v += __shfl_xor(v, 8);
    lp[r] = 1.0f / v;
  }

#pragma unroll
  for (int ct = 0; ct < 4; ++ct)
#pragma unroll
    for (int r = 0; r < 4; ++r)
      Og[(size_t)(qrow + r) * D_DIM + ct * 16 + l15] = oacc[ct][r] * lp[r];

  for (int kt = 0; kt < NT; ++kt) {
    __syncthreads();
    {
      const int r0 = tid >> 4;
      const int c  = (tid & 15) * 4;
      const float* Kt = Kg + kt * 64 * D_DIM;
#pragma unroll
      for (int i = 0; i < 4; ++i) {
        const int r = r0 + i * 16;
        float4 v = *(const float4*)(Kt + r * D_DIM + c);
        ushort4 p; p.x = f2bf(v.x); p.y = f2bf(v.y); p.z = f2bf(v.z); p.w = f2bf(v.w);
        *(ushort4*)(Ks + swz(r, c * 2)) = p;
      }
    }
    __syncthreads();

    unsigned long long mw[4] = {0, 0, 0, 0};
    if (USE_BITS) {
#pragma unroll
      for (int r = 0; r < 4; ++r) mw[r] = Mg[(qrow + r) * SW + kt];
    }

    f32x4 sacc[4];
#pragma unroll
    for (int i = 0; i < 4; ++i) sacc[i] = f32x4{0.f, 0.f, 0.f, 0.f};
#pragma unroll
    for (int ct = 0; ct < 4; ++ct) {
      s16x8 b0 = *(const s16x8*)(Ks + swz(ct * 16 + l15, g4 * 16));
      s16x8 b1 = *(const s16x8*)(Ks + swz(ct * 16 + l15, g4 * 16 + 64));
      sacc[ct] = mfma16(sacc[ct], qa0, b0);
      sacc[ct] = mfma16(sacc[ct], qa1, b1);
    }

#pragma unroll
    for (int ct = 0; ct < 4; ++ct) {
#pragma unroll
      for (int r = 0; r < 4; ++r) {
        float e = __expf(sacc[ct][r] * 0.125f);
        bool keep;
        if (USE_BITS) keep = (mw[r] >> (ct * 16 + l15)) & 1ull;
        else          keep = Mig[(size_t)(qrow + r) * S_LEN + kt * 64 + ct * 16 + l15] != 0;
        e = keep ? e : 0.f;
        __builtin_nontemporal_store(e * lp[r],
            Wg + (size_t)(qrow + r) * S_LEN + kt * 64 + ct * 16 + l15);
      }
    }
  }
}

extern "C" void kernel_launch(void* const* d_in, const int* in_sizes, int n_in,
                              void* d_out, int out_size, void* d_ws, size_t ws_size,
                              hipStream_t stream) {
  (void)in_sizes; (void)n_in; (void)out_size;
  const float* Q   = (const float*)d_in[0];
  const float* K   = (const float*)d_in[1];
  const float* V   = (const float*)d_in[2];
  const int* mask  = (const int*)d_in[3];
  float* Out = (float*)d_out;
  float* W   = Out + (size_t)B_NUM * H_NUM * S_LEN * D_DIM;

  const size_t bits_bytes = (size_t)(B_NUM * S_LEN * S_LEN / 64) * 8;      // 1 MiB
  const size_t t16_bytes  = (size_t)B_NUM * H_NUM * S_LEN * D_DIM * 2;     // 8 MiB
  unsigned long long* bits = (unsigned long long*)d_ws;

  if (ws_size >= bits_bytes + 3 * t16_bytes) {
    unsigned short* Q16 = (unsigned short*)((char*)d_ws + bits_bytes);
    unsigned short* K16 = Q16 + t16_bytes / 2;
    unsigned short* VT  = K16 + t16_bytes / 2;
    mask_pack_kernel<<<1024, 256, 0, stream>>>(mask, bits);
    cvt_qk_kernel<<<2048, 256, 0, stream>>>(Q, K, (u16x4*)Q16, (u16x4*)K16);
    v_transpose_kernel<<<1024, 256, 0, stream>>>(V, VT);
    attn_fused_kernel<<<1024, 256, 0, stream>>>(Q16, K16, VT, bits, Out, W);
  } else if (ws_size >= bits_bytes) {
    mask_pack_kernel<<<1024, 256, 0, stream>>>(mask, bits);
    attn_fwd_kernel<1><<<1024, 256, 0, stream>>>(Q, K, V, bits, mask, Out, W);
  } else {
    attn_fwd_kernel<0><<<1024, 256, 0, stream>>>(Q, K, V, bits, mask, Out, W);
  }
}